// Round 18
// baseline (50.595 us; speedup 1.0000x reference)
//
#include <hip/hip_runtime.h>
#include <hip/hip_fp16.h>

#define NTHREADS 256
#define NBLOCKS 2048
#define FB_NBLOCKS 2048
#define NB 1024          // lerp intervals

// Folded constants (derivation R9/R13):
//   KTOT = sqrt(2)*1.14136*e^2 ; CL_l = PATH_C_l * 0.25 / sqrt(10)
//   SH scales folded into packed node values; w_l(r)*CL_l in the r-LUT.
#define KTOT 11.9269705f
#define CL0  0.04564355f
#define CL1  0.02635231f
#define CL2  0.02041241f
#define S3   1.7320508f
#define S5   2.2360680f

__device__ __forceinline__ float fast_rcp(float x) { return __builtin_amdgcn_rcpf(x); }
__device__ __forceinline__ float fast_rsq(float x) {
    float r;
    asm("v_rsq_f32 %0, %1" : "=v"(r) : "v"(x));
    return r;
}

typedef float    vf4 __attribute__((ext_vector_type(4)));
typedef int      vi4 __attribute__((ext_vector_type(4)));
__device__ __forceinline__ float4 ntload4(const float4* p) {
    vf4 v = __builtin_nontemporal_load((const vf4*)p);
    return make_float4(v.x, v.y, v.z, v.w);
}
__device__ __forceinline__ int4 ntloadi4(const int4* p) {
    vi4 v = __builtin_nontemporal_load((const vi4*)p);
    return make_int4(v.x, v.y, v.z, v.w);
}

// ---------- w_l(r)*CL_l evaluator (exact math, prep only) ----------
__device__ __forceinline__ void eval_w(
    float r, const float* __restrict__ W1, const float* __restrict__ W2,
    float& w0, float& w1, float& w2)
{
    const float t    = 11.0f * r;
    const int   k0   = (int)t;
    const float frac = t - (float)k0;
    float ea = 0.0f, eb = 0.0f;
    if (k0 >= 1 && k0 <= 10) {
        const float da = fmaf(-frac, frac, 1.0f);
        if (da > 0.0226f) ea = KTOT * __expf(-2.0f * fast_rcp(da));
    }
    if (k0 <= 9) {
        const float db = frac * (2.0f - frac);
        if (db > 0.0226f) eb = KTOT * __expf(-2.0f * fast_rcp(db));
    }
    const int ra = min(max(k0 - 1, 0), 9);
    const int rb = min(k0, 9);
    w0 = 0.0f; w1 = 0.0f; w2 = 0.0f;
#pragma unroll
    for (int j = 0; j < 16; ++j) {
        const float h = fmaxf(fmaf(ea, W1[ra * 16 + j], eb * W1[rb * 16 + j]), 0.0f);
        w0 = fmaf(h, W2[j * 3 + 0], w0);
        w1 = fmaf(h, W2[j * 3 + 1], w1);
        w2 = fmaf(h, W2[j * 3 + 2], w2);
    }
    w0 *= CL0; w1 *= CL1; w2 *= CL2;
}

// ---------- fused prep: node packing + LUT records (PROVEN R17) ----------
__global__ __launch_bounds__(256) void prep_kernel(
    const float* __restrict__ nf,
    const float* __restrict__ W1, const float* __restrict__ W2,
    uint4* __restrict__ tab, uint4* __restrict__ wrec,
    int n_nodes, int pack_blocks)
{
    const int tid = threadIdx.x;
    if ((int)blockIdx.x < pack_blocks) {
        const int n = blockIdx.x * 256 + tid;
        if (n >= n_nodes) return;
        const float* f = nf + 9 * (size_t)n;
        const float scale[9] = { 1.0f, S3, S3, S3, S5 * S3, S5 * S3, S5, S5 * S3,
                                 0.5f * S5 * S3 };
        unsigned short hs[9];
#pragma unroll
        for (int i = 0; i < 9; ++i) {
            const __half h = __float2half_rn(f[i] * scale[i]);
            hs[i] = *reinterpret_cast<const unsigned short*>(&h);
        }
        unsigned long long c[9];
#pragma unroll
        for (int i = 1; i < 9; ++i)
            c[i] = (unsigned long long)(((unsigned)hs[i] + 2u) >> 2) & 0x3FFFull;
        const unsigned long long lo =
            c[1] | (c[2] << 14) | (c[3] << 28) | (c[4] << 42) | (c[5] << 56);
        const unsigned long long hi =
            (c[5] >> 8) | (c[6] << 6) | (c[7] << 20) | (c[8] << 34) |
            ((unsigned long long)hs[0] << 48);
        tab[n] = make_uint4((unsigned)lo, (unsigned)(lo >> 32),
                            (unsigned)hi, (unsigned)(hi >> 32));
    } else {
        const int i = ((int)blockIdx.x - pack_blocks) * 256 + tid;
        if (i >= NB) return;
        float w0a, w1a, w2a, w0b, w1b, w2b;
        eval_w((float)i       * (1.0f / (float)NB), W1, W2, w0a, w1a, w2a);
        eval_w((float)(i + 1) * (1.0f / (float)NB), W1, W2, w0b, w1b, w2b);
        auto hbits = [](float v) -> unsigned {
            const __half h = __float2half_rn(v);
            return (unsigned)*reinterpret_cast<const unsigned short*>(&h);
        };
        const unsigned b0 = hbits(w0a), b1 = hbits(w1a), b2 = hbits(w2a);
        const unsigned d0 = hbits(w0b - w0a), d1 = hbits(w1b - w1a), d2 = hbits(w2b - w2a);
        wrec[i] = make_uint4(b0 | (b1 << 16), b2 | (d0 << 16), d1 | (d2 << 16), 0u);
    }
}

// fp14/fp16 decode
__device__ __forceinline__ float cvt14(unsigned c) {
    __half_raw hr; hr.x = (unsigned short)(c << 2);
    return __half2float(*reinterpret_cast<const __half*>(&hr));
}
__device__ __forceinline__ float cvt16(unsigned c) {
    __half_raw hr; hr.x = (unsigned short)(c & 0xFFFFu);
    return __half2float(*reinterpret_cast<const __half*>(&hr));
}
__device__ __forceinline__ unsigned alignb(unsigned hi, unsigned lo, int s) {
    return (lo >> s) | (hi << (32 - s));
}

// ---------- per-edge term (PROVEN R16), rsqrtf -> raw v_rsq ----------
__device__ __forceinline__ float edge_term(
    float vx, float vy, float vz, uint4 g, const uint4* __restrict__ swq)
{
    const float r2 = fmaf(vx, vx, fmaf(vy, vy, vz * vz));
    const float rs = fast_rsq(fmaxf(r2, 1e-24f));
    const float r  = r2 * rs;
    const float x = vx * rs, y = vy * rs, z = vz * rs;

    const float tb = fminf(r, 1.0f) * (float)NB;
    const int   i  = min((int)tb, NB - 1);
    const float fb = tb - (float)i;
    const uint4 q = swq[i];   // single ds_read_b128
    const float wv0 = fmaf(fb, cvt16(q.y >> 16), cvt16(q.x));
    const float wv1 = fmaf(fb, cvt16(q.z),       cvt16(q.x >> 16));
    const float wv2 = fmaf(fb, cvt16(q.z >> 16), cvt16(q.y));

    const float fv1 = cvt14(g.x & 0x3FFFu);
    const float fv2 = cvt14((g.x >> 14) & 0x3FFFu);
    const float fv3 = cvt14(alignb(g.y, g.x, 28) & 0x3FFFu);
    const float fv4 = cvt14((g.y >> 10) & 0x3FFFu);
    const float fv5 = cvt14(alignb(g.z, g.y, 24) & 0x3FFFu);
    const float fv6 = cvt14((g.z >> 6) & 0x3FFFu);
    const float fv7 = cvt14(alignb(g.w, g.z, 20) & 0x3FFFu);
    const float fv8 = cvt14((g.w >> 2) & 0x3FFFu);
    const float f0  = cvt16(g.w >> 16);

    const float dots0 = f0;
    const float dots1 = fmaf(fv1, x, fmaf(fv2, y, fv3 * z));
    const float xx = x * x, yy = y * y, zz = z * z;
    const float dots2 = fmaf(fv4, x * z, fmaf(fv5, x * y,
                        fmaf(fv6, fmaf(-0.5f, xx + zz, yy),
                        fmaf(fv7, y * z, fv8 * (zz - xx)))));

    return fmaf(wv0, dots0, fmaf(wv1, dots1, wv2 * dots2));
}

// ---------- main: R16 structure; nt on STREAM loads only (tables stay cacheable) ----------
__global__ __launch_bounds__(NTHREADS) void edge_sum_nt(
    const float4* __restrict__ ev4,
    const int4*   __restrict__ src4,
    const uint4*  __restrict__ tab,
    const uint4*  __restrict__ wrec,
    float*        __restrict__ block_sums,
    int n_edges)
{
    __shared__ uint4 swq[NB];   // 16 KB
    const int tid = threadIdx.x;
    for (int i = tid; i < NB; i += NTHREADS) swq[i] = wrec[i];
    __syncthreads();

    float acc = 0.0f;
    const int n_groups = (n_edges + 3) >> 2;
    const int stride = gridDim.x * blockDim.x;
    for (int g = blockIdx.x * blockDim.x + tid; g < n_groups; g += stride) {
        const int e0 = g << 2;
        if (e0 + 3 < n_edges) {
            const float4 a = ntload4(ev4 + 3 * (size_t)g + 0);
            const float4 b = ntload4(ev4 + 3 * (size_t)g + 1);
            const float4 c = ntload4(ev4 + 3 * (size_t)g + 2);
            const int4   s = ntloadi4(src4 + g);
            const uint4 g0 = tab[s.x];
            const uint4 g1 = tab[s.y];
            const uint4 g2 = tab[s.z];
            const uint4 g3 = tab[s.w];
            acc += edge_term(a.x, a.y, a.z, g0, swq);
            acc += edge_term(a.w, b.x, b.y, g1, swq);
            acc += edge_term(b.z, b.w, c.x, g2, swq);
            acc += edge_term(c.y, c.z, c.w, g3, swq);
        } else {
            const float* evf  = reinterpret_cast<const float*>(ev4);
            const int*   srci = reinterpret_cast<const int*>(src4);
            for (int e = e0; e < n_edges; ++e) {
                acc += edge_term(evf[3 * (size_t)e], evf[3 * (size_t)e + 1],
                                 evf[3 * (size_t)e + 2], tab[srci[e]], swq);
            }
        }
    }

    // deterministic block reduction
#pragma unroll
    for (int off = 1; off < 64; off <<= 1)
        acc += __shfl_xor(acc, off, 64);
    __shared__ float wsum[NTHREADS / 64];
    const int lane = tid & 63, wid = tid >> 6;
    if (lane == 0) wsum[wid] = acc;
    __syncthreads();
    if (tid == 0) {
        float ssum = 0.0f;
#pragma unroll
        for (int w = 0; w < NTHREADS / 64; ++w) ssum += wsum[w];
        block_sums[blockIdx.x] = ssum;
    }
}

// ---------- fallback (round-2 proven path, exact math, f32 scalar gather) ----------
__global__ __launch_bounds__(NTHREADS) void edge_sum_fallback(
    const float* __restrict__ node_feats,
    const float* __restrict__ edge_vec,
    const float* __restrict__ W1,
    const float* __restrict__ W2,
    const int*   __restrict__ edge_src,
    float*       __restrict__ block_sums,
    int n_edges)
{
    __shared__ float4 sW1[10][5];
    float* sW1f = reinterpret_cast<float*>(sW1);
    const int tid = threadIdx.x;
    if (tid < 160) {
        sW1f[(tid >> 4) * 20 + (tid & 15)] = W1[tid];
    } else if (tid < 200) {
        const int i = tid - 160;
        sW1f[(i >> 2) * 20 + 16 + (i & 3)] = 0.0f;
    }
    __syncthreads();

    float w2r[16][3];
#pragma unroll
    for (int j = 0; j < 16; ++j) {
        w2r[j][0] = W2[j * 3 + 0] * CL0;
        w2r[j][1] = W2[j * 3 + 1] * CL1;
        w2r[j][2] = W2[j * 3 + 2] * CL2;
    }

    float acc = 0.0f;
    const int stride = gridDim.x * blockDim.x;
    for (int e = blockIdx.x * blockDim.x + tid; e < n_edges; e += stride) {
        const float vx = edge_vec[3 * (size_t)e + 0];
        const float vy = edge_vec[3 * (size_t)e + 1];
        const float vz = edge_vec[3 * (size_t)e + 2];
        const int   src = edge_src[e];
        const float* f = node_feats + 9 * (size_t)src;
        const float r2 = fmaf(vx, vx, fmaf(vy, vy, vz * vz));
        const float rs = rsqrtf(fmaxf(r2, 1e-24f));
        const float r  = r2 * rs;
        const float x = vx * rs, y = vy * rs, z = vz * rs;
        const float t    = 11.0f * r;
        const int   k0   = (int)t;
        const float frac = t - (float)k0;
        float ea = 0.0f, eb = 0.0f;
        if (k0 >= 1 && k0 <= 10) {
            const float da = fmaf(-frac, frac, 1.0f);
            if (da > 0.0226f) ea = KTOT * __expf(-2.0f * fast_rcp(da));
        }
        if (k0 <= 9) {
            const float db = frac * (2.0f - frac);
            if (db > 0.0226f) eb = KTOT * __expf(-2.0f * fast_rcp(db));
        }
        const int ra = min(max(k0 - 1, 0), 9);
        const int rb = min(k0, 9);
        const float4* rowA = &sW1[ra][0];
        const float4* rowB = &sW1[rb][0];
        float wv0 = 0.0f, wv1 = 0.0f, wv2 = 0.0f;
#pragma unroll
        for (int q = 0; q < 4; ++q) {
            const float4 A = rowA[q];
            const float4 B = rowB[q];
            float h;
            h = fmaxf(fmaf(ea, A.x, eb * B.x), 0.0f);
            wv0 = fmaf(h, w2r[4 * q + 0][0], wv0); wv1 = fmaf(h, w2r[4 * q + 0][1], wv1); wv2 = fmaf(h, w2r[4 * q + 0][2], wv2);
            h = fmaxf(fmaf(ea, A.y, eb * B.y), 0.0f);
            wv0 = fmaf(h, w2r[4 * q + 1][0], wv0); wv1 = fmaf(h, w2r[4 * q + 1][1], wv1); wv2 = fmaf(h, w2r[4 * q + 1][2], wv2);
            h = fmaxf(fmaf(ea, A.z, eb * B.z), 0.0f);
            wv0 = fmaf(h, w2r[4 * q + 2][0], wv0); wv1 = fmaf(h, w2r[4 * q + 2][1], wv1); wv2 = fmaf(h, w2r[4 * q + 2][2], wv2);
            h = fmaxf(fmaf(ea, A.w, eb * B.w), 0.0f);
            wv0 = fmaf(h, w2r[4 * q + 3][0], wv0); wv1 = fmaf(h, w2r[4 * q + 3][1], wv1); wv2 = fmaf(h, w2r[4 * q + 3][2], wv2);
        }
        const float f0 = f[0], f1 = f[1], f2 = f[2], f3 = f[3], f4 = f[4];
        const float f5 = f[5], f6 = f[6], f7 = f[7], f8 = f[8];
        const float dots0 = f0;
        const float dots1 = S3 * fmaf(f1, x, fmaf(f2, y, f3 * z));
        const float xx = x * x, yy = y * y, zz = z * z;
        const float sh20 = S5 * S3 * x * z;
        const float sh21 = S5 * S3 * x * y;
        const float sh22 = S5 * (yy - 0.5f * (xx + zz));
        const float sh23 = S5 * S3 * y * z;
        const float sh24 = S5 * 0.5f * S3 * (zz - xx);
        const float dots2 = fmaf(f4, sh20, fmaf(f5, sh21, fmaf(f6, sh22, fmaf(f7, sh23, f8 * sh24))));
        acc = fmaf(wv0, dots0, acc);
        acc = fmaf(wv1, dots1, acc);
        acc = fmaf(wv2, dots2, acc);
    }
#pragma unroll
    for (int off = 1; off < 64; off <<= 1)
        acc += __shfl_xor(acc, off, 64);
    __shared__ float wsum[NTHREADS / 64];
    const int lane = tid & 63, wid = tid >> 6;
    if (lane == 0) wsum[wid] = acc;
    __syncthreads();
    if (tid == 0) {
        float ssum = 0.0f;
#pragma unroll
        for (int w = 0; w < NTHREADS / 64; ++w) ssum += wsum[w];
        block_sums[blockIdx.x] = ssum;
    }
}

__global__ __launch_bounds__(256) void final_reduce_kernel(
    const float* __restrict__ block_sums, float* __restrict__ out, int n)
{
    const int tid = threadIdx.x;
    float acc = 0.0f;
    for (int i = tid; i < n; i += 256) acc += block_sums[i];
#pragma unroll
    for (int off = 1; off < 64; off <<= 1)
        acc += __shfl_xor(acc, off, 64);
    __shared__ float wsum[4];
    if ((tid & 63) == 0) wsum[tid >> 6] = acc;
    __syncthreads();
    if (tid == 0) out[0] = wsum[0] + wsum[1] + wsum[2] + wsum[3];
}

extern "C" void kernel_launch(void* const* d_in, const int* in_sizes, int n_in,
                              void* d_out, int out_size, void* d_ws, size_t ws_size,
                              hipStream_t stream) {
    const float* node_feats = (const float*)d_in[0];
    const float* edge_vec   = (const float*)d_in[1];
    const float* W1         = (const float*)d_in[2];
    const float* W2         = (const float*)d_in[3];
    const int*   edge_src   = (const int*)d_in[4];
    // d_in[5] (edge_dst) unused: segment_sum().sum() == plain sum over edges.
    const int n_edges = in_sizes[4];
    const int n_nodes = in_sizes[0] / 9;

    // ws layout: [block_sums 32KB][wrec NB*16B][node table N*16B]
    float* block_sums = (float*)d_ws;
    const size_t wrec_off = 32768;
    const size_t tab_off  = wrec_off + NB * 16;
    const size_t need     = tab_off + (size_t)n_nodes * 16;

    if (ws_size >= need) {
        uint4* wrec = (uint4*)((char*)d_ws + wrec_off);
        uint4* tab  = (uint4*)((char*)d_ws + tab_off);
        const int pack_blocks = (n_nodes + 255) / 256;
        const int lut_blocks  = NB / 256;   // 4
        prep_kernel<<<pack_blocks + lut_blocks, 256, 0, stream>>>(
            node_feats, W1, W2, tab, wrec, n_nodes, pack_blocks);
        edge_sum_nt<<<NBLOCKS, NTHREADS, 0, stream>>>(
            (const float4*)edge_vec, (const int4*)edge_src, tab, wrec,
            block_sums, n_edges);
        final_reduce_kernel<<<1, 256, 0, stream>>>(block_sums, (float*)d_out, NBLOCKS);
    } else {
        edge_sum_fallback<<<FB_NBLOCKS, NTHREADS, 0, stream>>>(
            node_feats, edge_vec, W1, W2, edge_src, block_sums, n_edges);
        final_reduce_kernel<<<1, 256, 0, stream>>>(block_sums, (float*)d_out, FB_NBLOCKS);
    }
}